// Round 1
// baseline (686.208 us; speedup 1.0000x reference)
//
#include <hip/hip_runtime.h>
#include <hip/hip_bf16.h>

// PDP unstructured soft-mask pruning, 8192x8192 f32.
// out = w * sigmoid((w^2 - t^2)/TEMP), t = 0.5*(desc[k0]+desc[k1]) of |w|,
// k0 = n/2, k1 = n/2+1 (descending ranks). Exact rank selection via 2-pass
// radix histogram on the IEEE bits of |w| (bit order == numeric order for
// non-negative floats).

constexpr int H1_BINS = 32768;   // top 15 bits of abs-bits (sign always 0)
constexpr int H2_BINS = 65536;   // low 16 bits

struct Sel {
    unsigned b0, r0, b1, r1;     // high-bin + within-bin descending rank, per target
    float    tsq;                // t*t
};

// ---------------- pass 1: 15-bit histogram, packed u16 LDS per block ---------
__global__ __launch_bounds__(256) void k_hist1(const float4* __restrict__ w4,
                                               unsigned* __restrict__ hist,
                                               long long n4) {
    __shared__ unsigned lh[H1_BINS / 2];       // 2x16-bit counters per word, 64 KB
    for (int i = threadIdx.x; i < H1_BINS / 2; i += 256) lh[i] = 0u;
    __syncthreads();
    const long long stride = (long long)gridDim.x * 256;
    for (long long i = (long long)blockIdx.x * 256 + threadIdx.x; i < n4; i += stride) {
        float4 v = w4[i];
        unsigned b;
        // per-block element count <= 32768 -> no carry across packed halves
        b = __float_as_uint(fabsf(v.x)) >> 16; atomicAdd(&lh[b >> 1], 1u << ((b & 1) * 16));
        b = __float_as_uint(fabsf(v.y)) >> 16; atomicAdd(&lh[b >> 1], 1u << ((b & 1) * 16));
        b = __float_as_uint(fabsf(v.z)) >> 16; atomicAdd(&lh[b >> 1], 1u << ((b & 1) * 16));
        b = __float_as_uint(fabsf(v.w)) >> 16; atomicAdd(&lh[b >> 1], 1u << ((b & 1) * 16));
    }
    __syncthreads();
    for (int i = threadIdx.x; i < H1_BINS / 2; i += 256) {
        unsigned v = lh[i];
        unsigned lo = v & 0xFFFFu, hi = v >> 16;
        if (lo) atomicAdd(&hist[2 * i],     lo);
        if (hi) atomicAdd(&hist[2 * i + 1], hi);
    }
}

// ---------------- scan 1: locate high bin + within-bin rank ------------------
__global__ __launch_bounds__(1024) void k_scan1(const unsigned* __restrict__ hist,
                                                Sel* __restrict__ sel,
                                                long long k0, long long k1) {
    __shared__ unsigned long long partial[1024];
    __shared__ unsigned long long suffix[1024];
    const int t = threadIdx.x;
    const int C = H1_BINS / 1024;              // 32 bins per thread
    unsigned long long s = 0;
    for (int j = 0; j < C; j++) s += hist[t * C + j];
    partial[t] = s;
    __syncthreads();
    if (t == 0) {
        unsigned long long acc = 0;
        for (int j = 1023; j >= 0; j--) { suffix[j] = acc; acc += partial[j]; }
    }
    __syncthreads();
    // descending traversal: cum = #elements in strictly higher bins
    unsigned long long cum = suffix[t];
    for (int j = C - 1; j >= 0; j--) {
        unsigned bin = (unsigned)(t * C + j);
        unsigned cnt = hist[bin];
        if (cnt) {
            if ((unsigned long long)k0 >= cum && (unsigned long long)k0 < cum + cnt) {
                sel->b0 = bin; sel->r0 = (unsigned)((unsigned long long)k0 - cum);
            }
            if ((unsigned long long)k1 >= cum && (unsigned long long)k1 < cum + cnt) {
                sel->b1 = bin; sel->r1 = (unsigned)((unsigned long long)k1 - cum);
            }
            cum += cnt;
        }
    }
}

// ---------------- pass 2: low-16-bit histogram of candidates -----------------
__global__ __launch_bounds__(256) void k_hist2(const float4* __restrict__ w4,
                                               const Sel* __restrict__ sel,
                                               unsigned* __restrict__ h2a,
                                               unsigned* __restrict__ h2b,
                                               long long n4) {
    const unsigned b0 = sel->b0, b1 = sel->b1;
    const long long stride = (long long)gridDim.x * 256;
    for (long long i = (long long)blockIdx.x * 256 + threadIdx.x; i < n4; i += stride) {
        float4 v = w4[i];
        unsigned bits;
        bits = __float_as_uint(fabsf(v.x));
        if ((bits >> 16) == b0) atomicAdd(&h2a[bits & 0xFFFFu], 1u);
        else if ((bits >> 16) == b1) atomicAdd(&h2b[bits & 0xFFFFu], 1u);
        bits = __float_as_uint(fabsf(v.y));
        if ((bits >> 16) == b0) atomicAdd(&h2a[bits & 0xFFFFu], 1u);
        else if ((bits >> 16) == b1) atomicAdd(&h2b[bits & 0xFFFFu], 1u);
        bits = __float_as_uint(fabsf(v.z));
        if ((bits >> 16) == b0) atomicAdd(&h2a[bits & 0xFFFFu], 1u);
        else if ((bits >> 16) == b1) atomicAdd(&h2b[bits & 0xFFFFu], 1u);
        bits = __float_as_uint(fabsf(v.w));
        if ((bits >> 16) == b0) atomicAdd(&h2a[bits & 0xFFFFu], 1u);
        else if ((bits >> 16) == b1) atomicAdd(&h2b[bits & 0xFFFFu], 1u);
    }
}

// ---------------- scan 2: exact values -> t^2 --------------------------------
__global__ __launch_bounds__(1024) void k_scan2(const unsigned* __restrict__ h2a,
                                                const unsigned* __restrict__ h2b,
                                                Sel* __restrict__ sel) {
    __shared__ unsigned long long partial[1024];
    __shared__ unsigned long long suffix[1024];
    __shared__ unsigned lowres[2];
    const int t = threadIdx.x;
    const unsigned b0 = sel->b0, b1 = sel->b1;
    const bool same = (b0 == b1);
    const unsigned long long r0 = sel->r0, r1 = sel->r1;
    const int C = H2_BINS / 1024;              // 64 bins per thread
    for (int phase = 0; phase < 2; phase++) {
        const unsigned* __restrict__ h = (phase == 0) ? h2a : h2b;
        if (phase == 1 && same) break;         // uniform branch, safe
        unsigned long long s = 0;
        for (int j = 0; j < C; j++) s += h[t * C + j];
        partial[t] = s;
        __syncthreads();
        if (t == 0) {
            unsigned long long acc = 0;
            for (int j = 1023; j >= 0; j--) { suffix[j] = acc; acc += partial[j]; }
        }
        __syncthreads();
        unsigned long long cum = suffix[t];
        for (int j = C - 1; j >= 0; j--) {
            unsigned bin = (unsigned)(t * C + j);
            unsigned cnt = h[bin];
            if (cnt) {
                if (phase == 0) {
                    if (r0 >= cum && r0 < cum + cnt) lowres[0] = bin;
                    if (same && r1 >= cum && r1 < cum + cnt) lowres[1] = bin;
                } else {
                    if (r1 >= cum && r1 < cum + cnt) lowres[1] = bin;
                }
                cum += cnt;
            }
        }
        __syncthreads();
    }
    if (t == 0) {
        float v0 = __uint_as_float((b0 << 16) | lowres[0]);
        float v1 = __uint_as_float((b1 << 16) | lowres[1]);
        float tt = 0.5f * (v0 + v1);
        sel->tsq = tt * tt;
    }
}

// ---------------- elementwise mask -------------------------------------------
__global__ __launch_bounds__(256) void k_mask(const float4* __restrict__ w4,
                                              float4* __restrict__ o4,
                                              const Sel* __restrict__ sel,
                                              long long n4) {
    const float tsq = sel->tsq;
    const long long stride = (long long)gridDim.x * 256;
    for (long long i = (long long)blockIdx.x * 256 + threadIdx.x; i < n4; i += stride) {
        float4 v = w4[i];
        float4 o;
        // w * sigmoid((w^2-t^2)/1e-5) = w / (1 + exp((t^2-w^2)*1e5))
        o.x = v.x / (1.0f + __expf((tsq - v.x * v.x) * 1e5f));
        o.y = v.y / (1.0f + __expf((tsq - v.y * v.y) * 1e5f));
        o.z = v.z / (1.0f + __expf((tsq - v.z * v.z) * 1e5f));
        o.w = v.w / (1.0f + __expf((tsq - v.w * v.w) * 1e5f));
        o4[i] = o;
    }
}

extern "C" void kernel_launch(void* const* d_in, const int* in_sizes, int n_in,
                              void* d_out, int out_size, void* d_ws, size_t ws_size,
                              hipStream_t stream) {
    const float* w = (const float*)d_in[0];
    float* out = (float*)d_out;
    const long long n  = (long long)in_sizes[0];
    const long long n4 = n / 4;                 // n = 2^26, divisible

    uint8_t* ws = (uint8_t*)d_ws;
    unsigned* hist1 = (unsigned*)ws;                                  // 128 KB
    unsigned* h2a   = (unsigned*)(ws + 131072);                       // 256 KB
    unsigned* h2b   = (unsigned*)(ws + 131072 + 262144);              // 256 KB
    Sel*      sel   = (Sel*)(ws + 131072 + 262144 + 262144);

    hipMemsetAsync(ws, 0, 131072 + 262144 + 262144 + sizeof(Sel), stream);

    long long lim = n / 2;                      // int((1-0.5)*n)
    if (lim > n - 2) lim = n - 2;
    const long long k0 = lim, k1 = lim + 1;

    // 2048 blocks -> 32768 elems/block -> packed-u16 LDS counters cannot overflow
    k_hist1<<<2048, 256, 0, stream>>>((const float4*)w, hist1, n4);
    k_scan1<<<1, 1024, 0, stream>>>(hist1, sel, k0, k1);
    k_hist2<<<2048, 256, 0, stream>>>((const float4*)w, sel, h2a, h2b, n4);
    k_scan2<<<1, 1024, 0, stream>>>(h2a, h2b, sel);
    k_mask<<<8192, 256, 0, stream>>>((const float4*)w, (float4*)out, sel, n4);
}

// Round 2
// 663.831 us; speedup vs baseline: 1.0337x; 1.0337x over previous
//
#include <hip/hip_runtime.h>
#include <hip/hip_bf16.h>
#include <stdint.h>

// PDP soft-mask pruning, 8192x8192 f32, exact median-of-|w| threshold via
// sample-guided bracketed selection (bit-exact, no distributional assumption
// beyond a DKW bracket with failure prob < 2e-128).

constexpr int H1_BINS = 32768;                 // top 15 bits of abs-bits
constexpr unsigned CAND_CAP = 1u << 22;        // 4M candidate slots (16 MB)
constexpr int NBLK_COMPACT = 4096;
constexpr int LCAP = 8192;                     // per-block candidate staging

struct Sel {
    unsigned b0, r0, b1, r1;   // bin + within-bin descending rank (two targets)
    float    tsq;
    unsigned cand_count;
};

// ---- sample histogram: 256 blocks x 16KB contiguous chunks = 2^20 floats ----
__global__ __launch_bounds__(256) void k_shist(const float4* __restrict__ w4,
                                               unsigned* __restrict__ hist,
                                               long long n4) {
    __shared__ unsigned lh[H1_BINS / 2];
    for (int i = threadIdx.x; i < H1_BINS / 2; i += 256) lh[i] = 0u;
    __syncthreads();
    const long long base = (long long)blockIdx.x * (n4 >> 8);
    for (int j = 0; j < 4; j++) {
        long long idx = base + j * 256 + threadIdx.x;
        if (idx < n4) {
            float4 v = w4[idx];
            unsigned b;
            b = __float_as_uint(fabsf(v.x)) >> 16; atomicAdd(&lh[b >> 1], 1u << ((b & 1) * 16));
            b = __float_as_uint(fabsf(v.y)) >> 16; atomicAdd(&lh[b >> 1], 1u << ((b & 1) * 16));
            b = __float_as_uint(fabsf(v.z)) >> 16; atomicAdd(&lh[b >> 1], 1u << ((b & 1) * 16));
            b = __float_as_uint(fabsf(v.w)) >> 16; atomicAdd(&lh[b >> 1], 1u << ((b & 1) * 16));
        }
    }
    __syncthreads();
    for (int i = threadIdx.x; i < H1_BINS / 2; i += 256) {
        unsigned v = lh[i];
        unsigned lo = v & 0xFFFFu, hi = v >> 16;
        if (lo) atomicAdd(&hist[2 * i],     lo);
        if (hi) atomicAdd(&hist[2 * i + 1], hi);
    }
}

// ---- generic descending scan over a 32768-bin hist; optional rank offset ----
// If above_arr != nullptr, k0/k1 are first reduced by sum(above_arr[0..above_n)).
__global__ __launch_bounds__(1024) void k_scan1(const unsigned* __restrict__ hist,
                                                Sel* __restrict__ sel,
                                                const unsigned long long* __restrict__ above_arr,
                                                int above_n,
                                                long long k0, long long k1) {
    __shared__ unsigned long long partial[1024];
    __shared__ unsigned long long suffix[1024];
    __shared__ unsigned long long redbuf[1024];
    const int t = threadIdx.x;
    if (above_arr) {
        unsigned long long a = 0;
        for (int i = t; i < above_n; i += 1024) a += above_arr[i];
        redbuf[t] = a;
        __syncthreads();
        for (int s = 512; s > 0; s >>= 1) {
            if (t < s) redbuf[t] += redbuf[t + s];
            __syncthreads();
        }
        k0 -= (long long)redbuf[0];
        k1 -= (long long)redbuf[0];
        __syncthreads();
    }
    const int C = H1_BINS / 1024;
    unsigned long long s = 0;
    for (int j = 0; j < C; j++) s += hist[t * C + j];
    partial[t] = s;
    __syncthreads();
    if (t == 0) {
        unsigned long long acc = 0;
        for (int j = 1023; j >= 0; j--) { suffix[j] = acc; acc += partial[j]; }
    }
    __syncthreads();
    unsigned long long cum = suffix[t];
    for (int j = C - 1; j >= 0; j--) {
        unsigned bin = (unsigned)(t * C + j);
        unsigned cnt = hist[bin];
        if (cnt) {
            if ((unsigned long long)k0 >= cum && (unsigned long long)k0 < cum + cnt) {
                sel->b0 = bin; sel->r0 = (unsigned)((unsigned long long)k0 - cum);
            }
            if ((unsigned long long)k1 >= cum && (unsigned long long)k1 < cum + cnt) {
                sel->b1 = bin; sel->r1 = (unsigned)((unsigned long long)k1 - cum);
            }
            cum += cnt;
        }
    }
}

// ---- full pass: count above-bracket, compact bracketed candidates ----------
// selS->b0 = BH (bin at sample rank m/2-c), selS->b1 = BL (rank m/2+c).
__global__ __launch_bounds__(256) void k_compact(const float4* __restrict__ w4,
                                                 Sel* sel,
                                                 unsigned* __restrict__ cand,
                                                 unsigned long long* __restrict__ above_arr,
                                                 long long n4) {
    __shared__ unsigned lbuf[LCAP];
    __shared__ unsigned lcnt;
    __shared__ unsigned gbase;
    if (threadIdx.x == 0) lcnt = 0;
    __syncthreads();
    const unsigned BH = sel->b0, BL = sel->b1;
    unsigned my_above = 0;
    const long long stride = (long long)gridDim.x * 256;
    for (long long i = (long long)blockIdx.x * 256 + threadIdx.x; i < n4; i += stride) {
        float4 v = w4[i];
        #pragma unroll
        for (int c = 0; c < 4; c++) {
            float f = (c == 0) ? v.x : (c == 1) ? v.y : (c == 2) ? v.z : v.w;
            unsigned bits = __float_as_uint(fabsf(f));
            unsigned bin = bits >> 16;
            my_above += (bin > BH) ? 1u : 0u;
            if (bin >= BL && bin <= BH) {
                unsigned p = atomicAdd(&lcnt, 1u);
                if (p < LCAP) lbuf[p] = bits;
            }
        }
    }
    // wave-reduce above, one LDS-free store per wave into per-block slot
    #pragma unroll
    for (int off = 32; off > 0; off >>= 1)
        my_above += __shfl_down(my_above, off, 64);
    __shared__ unsigned long long wsum[4];
    const int wid = threadIdx.x >> 6;
    if ((threadIdx.x & 63) == 0) wsum[wid] = my_above;
    __syncthreads();
    if (threadIdx.x == 0) {
        above_arr[blockIdx.x] = wsum[0] + wsum[1] + wsum[2] + wsum[3];
        unsigned cnt = lcnt < LCAP ? lcnt : LCAP;
        gbase = atomicAdd(&sel->cand_count, cnt);
    }
    __syncthreads();
    const unsigned cnt = lcnt < LCAP ? lcnt : LCAP;
    for (unsigned i = threadIdx.x; i < cnt; i += 256) {
        unsigned dst = gbase + i;
        if (dst < CAND_CAP) cand[dst] = lbuf[i];
    }
}

// ---- 15-bit histogram over the compacted candidates ------------------------
__global__ __launch_bounds__(256) void k_chist(const unsigned* __restrict__ cand,
                                               const Sel* __restrict__ selS,
                                               unsigned* __restrict__ hist) {
    __shared__ unsigned lh[H1_BINS / 2];
    for (int i = threadIdx.x; i < H1_BINS / 2; i += 256) lh[i] = 0u;
    __syncthreads();
    unsigned count = selS->cand_count;
    if (count > CAND_CAP) count = CAND_CAP;
    const unsigned stride = gridDim.x * 256;
    for (unsigned i = blockIdx.x * 256 + threadIdx.x; i < count; i += stride) {
        unsigned b = cand[i] >> 16;
        atomicAdd(&lh[b >> 1], 1u << ((b & 1) * 16));
    }
    __syncthreads();
    for (int i = threadIdx.x; i < H1_BINS / 2; i += 256) {
        unsigned v = lh[i];
        unsigned lo = v & 0xFFFFu, hi = v >> 16;
        if (lo) atomicAdd(&hist[2 * i],     lo);
        if (hi) atomicAdd(&hist[2 * i + 1], hi);
    }
}

// ---- low-16-bit histogram of candidates in the two selected bins -----------
__global__ __launch_bounds__(256) void k_chist2(const unsigned* __restrict__ cand,
                                                const Sel* __restrict__ selS,
                                                const Sel* __restrict__ selC,
                                                unsigned* __restrict__ h2a,
                                                unsigned* __restrict__ h2b) {
    const unsigned b0 = selC->b0, b1 = selC->b1;
    unsigned count = selS->cand_count;
    if (count > CAND_CAP) count = CAND_CAP;
    const unsigned stride = gridDim.x * 256;
    for (unsigned i = blockIdx.x * 256 + threadIdx.x; i < count; i += stride) {
        unsigned bits = cand[i];
        unsigned hi = bits >> 16;
        if (hi == b0) atomicAdd(&h2a[bits & 0xFFFFu], 1u);
        else if (hi == b1) atomicAdd(&h2b[bits & 0xFFFFu], 1u);
    }
}

// ---- resolve low 16 bits -> exact t^2 ---------------------------------------
__global__ __launch_bounds__(1024) void k_scan2(const unsigned* __restrict__ h2a,
                                                const unsigned* __restrict__ h2b,
                                                Sel* __restrict__ sel) {
    __shared__ unsigned long long partial[1024];
    __shared__ unsigned long long suffix[1024];
    __shared__ unsigned lowres[2];
    const int t = threadIdx.x;
    const unsigned b0 = sel->b0, b1 = sel->b1;
    const bool same = (b0 == b1);
    const unsigned long long r0 = sel->r0, r1 = sel->r1;
    const int C = 65536 / 1024;
    for (int phase = 0; phase < 2; phase++) {
        const unsigned* __restrict__ h = (phase == 0) ? h2a : h2b;
        if (phase == 1 && same) break;
        unsigned long long s = 0;
        for (int j = 0; j < C; j++) s += h[t * C + j];
        partial[t] = s;
        __syncthreads();
        if (t == 0) {
            unsigned long long acc = 0;
            for (int j = 1023; j >= 0; j--) { suffix[j] = acc; acc += partial[j]; }
        }
        __syncthreads();
        unsigned long long cum = suffix[t];
        for (int j = C - 1; j >= 0; j--) {
            unsigned bin = (unsigned)(t * C + j);
            unsigned cnt = h[bin];
            if (cnt) {
                if (phase == 0) {
                    if (r0 >= cum && r0 < cum + cnt) lowres[0] = bin;
                    if (same && r1 >= cum && r1 < cum + cnt) lowres[1] = bin;
                } else {
                    if (r1 >= cum && r1 < cum + cnt) lowres[1] = bin;
                }
                cum += cnt;
            }
        }
        __syncthreads();
    }
    if (t == 0) {
        float v0 = __uint_as_float((b0 << 16) | lowres[0]);
        float v1 = __uint_as_float((b1 << 16) | lowres[1]);
        float tt = 0.5f * (v0 + v1);
        sel->tsq = tt * tt;
    }
}

// ---- elementwise mask -------------------------------------------------------
__global__ __launch_bounds__(256) void k_mask(const float4* __restrict__ w4,
                                              float4* __restrict__ o4,
                                              const Sel* __restrict__ sel,
                                              long long n4) {
    const float tsq = sel->tsq;
    const long long stride = (long long)gridDim.x * 256;
    for (long long i = (long long)blockIdx.x * 256 + threadIdx.x; i < n4; i += stride) {
        float4 v = w4[i];
        float4 o;
        o.x = v.x / (1.0f + __expf((tsq - v.x * v.x) * 1e5f));
        o.y = v.y / (1.0f + __expf((tsq - v.y * v.y) * 1e5f));
        o.z = v.z / (1.0f + __expf((tsq - v.z * v.z) * 1e5f));
        o.w = v.w / (1.0f + __expf((tsq - v.w * v.w) * 1e5f));
        o4[i] = o;
    }
}

extern "C" void kernel_launch(void* const* d_in, const int* in_sizes, int n_in,
                              void* d_out, int out_size, void* d_ws, size_t ws_size,
                              hipStream_t stream) {
    const float* w = (const float*)d_in[0];
    float* out = (float*)d_out;
    const long long n  = (long long)in_sizes[0];
    const long long n4 = n / 4;

    uint8_t* ws = (uint8_t*)d_ws;
    unsigned*           hist_s    = (unsigned*)ws;                         // 128 KB
    unsigned*           chist     = (unsigned*)(ws + 131072);              // 128 KB
    unsigned*           h2a       = (unsigned*)(ws + 262144);              // 256 KB
    unsigned*           h2b       = (unsigned*)(ws + 524288);              // 256 KB
    Sel*                selS      = (Sel*)(ws + 786432);
    Sel*                selC      = (Sel*)(ws + 786432 + 64);
    unsigned long long* above_arr = (unsigned long long*)(ws + 786432 + 128); // 32 KB
    unsigned*           cand      = (unsigned*)(ws + 1048576);             // 16 MB

    hipMemsetAsync(ws, 0, 786432 + 128 + NBLK_COMPACT * sizeof(unsigned long long), stream);

    long long lim = n / 2;
    if (lim > n - 2) lim = n - 2;
    const long long k0 = lim, k1 = lim + 1;

    // sample: 256 blocks x 4096 floats = 2^20; bracket c = 8192 sample ranks
    const long long m = 256LL * 4096;
    const long long c = 8192;
    const long long rhi = m / 2 - c;   // -> BH (stored in selS->b0)
    const long long rlo = m / 2 + c;   // -> BL (stored in selS->b1)

    k_shist  <<<256, 256, 0, stream>>>((const float4*)w, hist_s, n4);
    k_scan1  <<<1, 1024, 0, stream>>>(hist_s, selS, nullptr, 0, rhi, rlo);
    k_compact<<<NBLK_COMPACT, 256, 0, stream>>>((const float4*)w, selS, cand, above_arr, n4);
    k_chist  <<<256, 256, 0, stream>>>(cand, selS, chist);
    k_scan1  <<<1, 1024, 0, stream>>>(chist, selC, above_arr, NBLK_COMPACT, k0, k1);
    k_chist2 <<<256, 256, 0, stream>>>(cand, selS, selC, h2a, h2b);
    k_scan2  <<<1, 1024, 0, stream>>>(h2a, h2b, selC);
    k_mask   <<<8192, 256, 0, stream>>>((const float4*)w, (float4*)out, selC, n4);
}